// Round 9
// baseline (181.787 us; speedup 1.0000x reference)
//
#include <hip/hip_runtime.h>

// BaseAttention: B=2 H=16 S=2048 D=64, fp32 in/out.
// Round 9: barrier-free streaming flash attention.
//   Round-8 lesson: all pipes <26% busy, occupancy 18% -> latency-bound on
//   the barrier'd LDS round-trip. Every LDS read was a per-lane 16B fragment
//   at a static (lane,kt) address -> prep now stores K/V fragments in
//   WAVE-READ ORDER in global: kf[bh][kt][ks*2+frag][lane] (16B). Main
//   kernel global-loads A-fragments directly (coalesced 1KB/instr, L2/L3
//   resident): NO LDS, NO barriers, NO DMA drain. K frags prefetched one
//   tile ahead in registers; V/mask issued at iter top, used ~300cyc later.
//   Mask AND-words relaid [kt][row][hl][16] so a wave's 4KB/tile is
//   contiguous (L1 reuse across the 4 uint4 loads).
//   Softmax: exp2 (Q pre-scaled by 0.125*log2e), f16 P via pkrtz, mask via
//   AND-words, l via ones-MFMA. P->B-frags via half-wave shfl (no LDS).

#define S_LEN 2048
#define D_DIM 64
#define N_KT 32
#define NBH 32
#define TILE_FR 4096  // shorts per fragment-tile image (8KB)

typedef __attribute__((ext_vector_type(8))) short bf16x8;
typedef __attribute__((ext_vector_type(16))) float f32x16;
typedef __attribute__((ext_vector_type(2))) __fp16 fp16x2;
typedef unsigned int u32;
typedef unsigned long long u64;

#define C1 0.180336880111121f    // 0.125 * log2(e)
#define CM (-14426.9504088896f)  // -10000 * log2(e)  (fallback kernel only)
#define LDK 72                   // fallback kernel only
#define LDV 72

static __device__ __forceinline__ unsigned short f2bf(float f) {
  union { float f; unsigned u; } x; x.f = f;
  return (unsigned short)((x.u + 0x8000u) >> 16);
}
static __device__ __forceinline__ unsigned packbf(float lo, float hi) {
  union { float f; unsigned u; } a, b; a.f = lo; b.f = hi;
  return ((a.u + 0x8000u) >> 16) | ((b.u + 0x8000u) & 0xffff0000u);
}
static __device__ __forceinline__ f32x16 zero16() {
  f32x16 z;
#pragma unroll
  for (int i = 0; i < 16; ++i) z[i] = 0.f;
  return z;
}
static __device__ __forceinline__ unsigned pkh(float lo, float hi) {
  union { fp16x2 h; unsigned u; } x;
  x.h = __builtin_amdgcn_cvt_pkrtz(lo, hi);
  return x.u;
}
static __device__ __forceinline__ unsigned short f2h(float f) {
  union { fp16x2 h; unsigned u; } x;
  x.h = __builtin_amdgcn_cvt_pkrtz(f, f);
  return (unsigned short)x.u;
}

// ---- pre-pass: K/V -> fragment images in wave-read order ----
// K frag (ks,frag,lane=hl*32+col) = bf16 K[key=col+frag*32][d=ks*16+hl*8..+8]
// V frag (ks,frag,lane)           = f16  V[j=ks*16+hl*8..+8][d=col+frag*32]
__global__ __launch_bounds__(256) void prep_kvf(
    const float* __restrict__ k, const float* __restrict__ v,
    unsigned short* __restrict__ kfw, unsigned short* __restrict__ vfw) {
  const int kt = blockIdx.x, bh = blockIdx.y;
  const int t = threadIdx.x;
  const size_t goff = (size_t)bh * (S_LEN * D_DIM) + (size_t)kt * 64 * D_DIM;
  const float4* kg = (const float4*)(k + goff);
  const float4* vg = (const float4*)(v + goff);
  unsigned short* kimg = kfw + (size_t)(bh * N_KT + kt) * TILE_FR;
  unsigned short* vimg = vfw + (size_t)(bh * N_KT + kt) * TILE_FR;
#pragma unroll
  for (int j = 0; j < 4; ++j) {
    const int i = t + j * 256;
    const int row = i >> 4, c4 = i & 15;
    // K: row = key, c4 = d-group
    {
      const float4 x = kg[i];
      const int frag = row >> 5, colr = row & 31;
      const int ks = c4 >> 2, hlk = (c4 >> 1) & 1, half = c4 & 1;
      ushort4 w;
      w.x = f2bf(x.x); w.y = f2bf(x.y); w.z = f2bf(x.z); w.w = f2bf(x.w);
      *(ushort4*)&kimg[((ks * 2 + frag) * 64 + hlk * 32 + colr) * 8 + half * 4] = w;
    }
    // V: row = j (key), c4*4+e = d
    {
      const float4 y = vg[i];
      const int ksv = row >> 4, hlv = (row >> 3) & 1, pos = row & 7;
      const float* yp = &y.x;
#pragma unroll
      for (int e = 0; e < 4; ++e) {
        const int d = c4 * 4 + e;
        vimg[((ksv * 2 + (d >> 5)) * 64 + hlv * 32 + (d & 31)) * 8 + pos] =
            f2h(yp[e]);
      }
    }
  }
}

// ---- pre-pass: mask -> u32 AND-words, [kt][row][hl][16] layout ----
__global__ __launch_bounds__(256) void prep_mask(
    const int* __restrict__ mask, u32* __restrict__ mw) {
  const int wid = blockIdx.x * 4 + (threadIdx.x >> 6);  // row*32 + kt
  const int lane = threadIdx.x & 63;
  const int row = wid >> 5, kt = wid & 31;
  const int mv = mask[(size_t)row * S_LEN + kt * 64 + lane];
  const u64 b = __ballot(mv != 0);
  if (lane < 32) {
    const int hl = lane >> 4, p = lane & 15;
    const int kb = p >> 3, g = (p >> 1) & 3, h = p & 1;
    const int j0 = 32 * kb + 8 * g + 4 * hl + 2 * h;
    u32 w = 0;
    if (!((b >> j0) & 1)) w |= 0x0000FFFFu;
    if (!((b >> (j0 + 1)) & 1)) w |= 0xFFFF0000u;
    mw[(((size_t)kt * S_LEN + row) * 2 + hl) * 16 + p] = w;
  }
}

// ---- main: barrier-free streaming flash attention ----
__global__ __launch_bounds__(128, 2) void attn_fwd(
    const float* __restrict__ q, const unsigned short* __restrict__ kf,
    const unsigned short* __restrict__ vf, const u32* __restrict__ mw,
    float* __restrict__ out) {
  const int qt = blockIdx.x;  // 0..31 (64 q rows per block)
  const int bh = blockIdx.y;  // 0..31
  const size_t hoff = (size_t)bh * (S_LEN * D_DIM);

  const int t = threadIdx.x;
  const int wave = t >> 6;
  const int lane = t & 63;
  const int col = lane & 31;
  const int hl = lane >> 5;

  const int qg = qt * 64 + wave * 32 + col;  // this lane's q row within head

  // Q^T B-fragments from global, PRE-SCALED by C1: B[k=d][n=q]
  bf16x8 bQ[4];
  {
    const float* qrow = q + hoff + (size_t)qg * D_DIM;
#pragma unroll
    for (int ks = 0; ks < 4; ++ks) {
      const float4 x0 = *(const float4*)(qrow + ks * 16 + hl * 8);
      const float4 x1 = *(const float4*)(qrow + ks * 16 + hl * 8 + 4);
      union { bf16x8 v; unsigned d[4]; } u;
      u.d[0] = packbf(x0.x * C1, x0.y * C1);
      u.d[1] = packbf(x0.z * C1, x0.w * C1);
      u.d[2] = packbf(x1.x * C1, x1.y * C1);
      u.d[3] = packbf(x1.z * C1, x1.w * C1);
      bQ[ks] = u.v;
    }
  }

  // ones A-fragment (f16 1.0) for the l row-sum MFMA
  bf16x8 onesA;
  {
    union { bf16x8 v; unsigned d[4]; } u;
    u.d[0] = u.d[1] = u.d[2] = u.d[3] = 0x3C003C00u;
    onesA = u.v;
  }

  // per-lane fragment base pointers (lane term folded in)
  const unsigned short* kbase =
      kf + (size_t)bh * N_KT * TILE_FR + (size_t)lane * 8;
  const unsigned short* vbase =
      vf + (size_t)bh * N_KT * TILE_FR + (size_t)lane * 8;
  const uint4* mrow = (const uint4*)mw + ((size_t)qg * 2 + hl) * 4;

  f32x16 oT0 = zero16(), oT1 = zero16(), oL = zero16();

  bf16x8 kc[8], kn[8], vc[8];
#pragma unroll
  for (int i = 0; i < 8; ++i) kc[i] = *(const bf16x8*)(kbase + i * 512);

  for (int kt = 0; kt < N_KT; ++kt) {
    // V fragments + mask for CURRENT tile (used ~300cyc later: latency ok)
    const unsigned short* vt = vbase + (size_t)kt * TILE_FR;
#pragma unroll
    for (int i = 0; i < 8; ++i) vc[i] = *(const bf16x8*)(vt + i * 512);
    const uint4* mt = mrow + (size_t)kt * (S_LEN * 2 * 4);
    const uint4 m0 = mt[0], m1 = mt[1], m2 = mt[2], m3 = mt[3];
    // K fragments for NEXT tile
    if (kt + 1 < N_KT) {
      const unsigned short* nt = kbase + (size_t)(kt + 1) * TILE_FR;
#pragma unroll
      for (int i = 0; i < 8; ++i) kn[i] = *(const bf16x8*)(nt + i * 512);
    }

    // S^T = K Q^T : 2 key-blocks x 4 k-steps (scores pre-scaled via Q)
    f32x16 sT0 = zero16(), sT1 = zero16();
#pragma unroll
    for (int ks = 0; ks < 4; ++ks) {
      sT0 = __builtin_amdgcn_mfma_f32_32x32x16_bf16(kc[ks * 2 + 0], bQ[ks], sT0, 0, 0, 0);
      sT1 = __builtin_amdgcn_mfma_f32_32x32x16_bf16(kc[ks * 2 + 1], bQ[ks], sT1, 0, 0, 0);
    }

    // p = exp2(s), pack f16 pairs, mask with AND-words
    const u32 mwv[16] = {m0.x, m0.y, m0.z, m0.w, m1.x, m1.y, m1.z, m1.w,
                         m2.x, m2.y, m2.z, m2.w, m3.x, m3.y, m3.z, m3.w};
    unsigned pw[16];
#pragma unroll
    for (int kb = 0; kb < 2; ++kb) {
      const f32x16 sT = kb ? sT1 : sT0;
#pragma unroll
      for (int g = 0; g < 4; ++g) {
        const float e0 = __builtin_amdgcn_exp2f(sT[g * 4 + 0]);
        const float e1 = __builtin_amdgcn_exp2f(sT[g * 4 + 1]);
        const float e2 = __builtin_amdgcn_exp2f(sT[g * 4 + 2]);
        const float e3 = __builtin_amdgcn_exp2f(sT[g * 4 + 3]);
        pw[kb * 8 + g * 2 + 0] = pkh(e0, e1) & mwv[kb * 8 + g * 2 + 0];
        pw[kb * 8 + g * 2 + 1] = pkh(e2, e3) & mwv[kb * 8 + g * 2 + 1];
      }
    }

    // O^T += Vt * P^T ; l += ones * P^T (P^T B-frags via half-wave shfl)
#pragma unroll
    for (int ks = 0; ks < 4; ++ks) {
      const int kb = ks >> 1, h = ks & 1;
      const unsigned d0 = pw[kb * 8 + 4 * h + 0], d1 = pw[kb * 8 + 4 * h + 1];
      const unsigned d2 = pw[kb * 8 + 4 * h + 2], d3 = pw[kb * 8 + 4 * h + 3];
      const unsigned s0 = hl ? d0 : d2;
      const unsigned s1 = hl ? d1 : d3;
      const unsigned r0 = (unsigned)__shfl_xor((int)s0, 32);
      const unsigned r1 = (unsigned)__shfl_xor((int)s1, 32);
      union { bf16x8 v; unsigned d[4]; } pf;
      pf.d[0] = hl ? r0 : d0;
      pf.d[1] = hl ? r1 : d1;
      pf.d[2] = hl ? d2 : r0;
      pf.d[3] = hl ? d3 : r1;
      oT0 = __builtin_amdgcn_mfma_f32_32x32x16_f16(vc[ks * 2 + 0], pf.v, oT0, 0, 0, 0);
      oT1 = __builtin_amdgcn_mfma_f32_32x32x16_f16(vc[ks * 2 + 1], pf.v, oT1, 0, 0, 0);
      oL = __builtin_amdgcn_mfma_f32_32x32x16_f16(onesA, pf.v, oL, 0, 0, 0);
    }

#pragma unroll
    for (int i = 0; i < 8; ++i) kc[i] = kn[i];
  }

  const float inv = 1.0f / oL[0];  // every C row of ones*P^T equals l(q=col)
  float* orow = out + hoff + (size_t)qg * D_DIM;
#pragma unroll
  for (int rg = 0; rg < 4; ++rg) {
    float4 w0, w1;
    w0.x = oT0[rg * 4 + 0] * inv; w0.y = oT0[rg * 4 + 1] * inv;
    w0.z = oT0[rg * 4 + 2] * inv; w0.w = oT0[rg * 4 + 3] * inv;
    w1.x = oT1[rg * 4 + 0] * inv; w1.y = oT1[rg * 4 + 1] * inv;
    w1.z = oT1[rg * 4 + 2] * inv; w1.w = oT1[rg * 4 + 3] * inv;
    *(float4*)(orow + 8 * rg + 4 * hl) = w0;
    *(float4*)(orow + 32 + 8 * rg + 4 * hl) = w1;
  }
}

// ---- fallback (round-4 style, self-staging) if ws is too small ----
__global__ __launch_bounds__(256, 2) void attn_fwd_self(
    const float* __restrict__ q, const float* __restrict__ k,
    const float* __restrict__ v, const int* __restrict__ mask,
    float* __restrict__ out) {
  const int qt = blockIdx.x;
  const int bh = blockIdx.y;
  const size_t hoff = (size_t)bh * (S_LEN * D_DIM);
  __shared__ unsigned short Ks[64 * LDK];
  __shared__ unsigned short Vt[64 * LDV];
  const int t = threadIdx.x;
  const int wave = t >> 6;
  const int lane = t & 63;
  const int col = lane & 31;
  const int hl = lane >> 5;
  const int sw = col >> 2;
  const int qg = qt * 128 + wave * 32 + col;
  bf16x8 bQ[4];
  {
    const float* qrow = q + hoff + (size_t)qg * D_DIM;
#pragma unroll
    for (int ks = 0; ks < 4; ++ks) {
      const float4 x0 = *(const float4*)(qrow + ks * 16 + hl * 8);
      const float4 x1 = *(const float4*)(qrow + ks * 16 + hl * 8 + 4);
      union { bf16x8 v; unsigned d[4]; } u;
      u.d[0] = packbf(x0.x, x0.y);
      u.d[1] = packbf(x0.z, x0.w);
      u.d[2] = packbf(x1.x, x1.y);
      u.d[3] = packbf(x1.z, x1.w);
      bQ[ks] = u.v;
    }
  }
  float4 pk[4], pv[4];
  {
    const float4* kg = (const float4*)(k + hoff);
    const float4* vg = (const float4*)(v + hoff);
#pragma unroll
    for (int j = 0; j < 4; ++j) { pk[j] = kg[t + j * 256]; pv[j] = vg[t + j * 256]; }
  }
  f32x16 oT0 = zero16(), oT1 = zero16();
  float lacc = 0.f;
  const int* mrow = mask + (size_t)qg * S_LEN;
  for (int kt = 0; kt < N_KT; ++kt) {
    __syncthreads();
#pragma unroll
    for (int j = 0; j < 4; ++j) {
      const int i = t + j * 256;
      const int row = i >> 4, c4 = i & 15;
      ushort4 w;
      w.x = f2bf(pk[j].x); w.y = f2bf(pk[j].y);
      w.z = f2bf(pk[j].z); w.w = f2bf(pk[j].w);
      *(ushort4*)&Ks[row * LDK + c4 * 4] = w;
      const int swc = 8 * (((row >> 3) + c4) & 7) + (row & 7);
      Vt[(4 * c4 + 0) * LDV + swc] = f2bf(pv[j].x);
      Vt[(4 * c4 + 1) * LDV + swc] = f2bf(pv[j].y);
      Vt[(4 * c4 + 2) * LDV + swc] = f2bf(pv[j].z);
      Vt[(4 * c4 + 3) * LDV + swc] = f2bf(pv[j].w);
    }
    __syncthreads();
    if (kt + 1 < N_KT) {
      const float4* kg = (const float4*)(k + hoff + (size_t)(kt + 1) * 64 * D_DIM);
      const float4* vg = (const float4*)(v + hoff + (size_t)(kt + 1) * 64 * D_DIM);
#pragma unroll
      for (int j = 0; j < 4; ++j) { pk[j] = kg[t + j * 256]; pv[j] = vg[t + j * 256]; }
    }
    int4 mq[2][4];
#pragma unroll
    for (int kb = 0; kb < 2; ++kb)
#pragma unroll
      for (int g = 0; g < 4; ++g)
        mq[kb][g] = *(const int4*)(mrow + kt * 64 + kb * 32 + g * 8 + hl * 4);
    f32x16 sT0 = zero16(), sT1 = zero16();
#pragma unroll
    for (int ks = 0; ks < 4; ++ks) {
      const bf16x8 aK0 = *(const bf16x8*)&Ks[col * LDK + ks * 16 + hl * 8];
      const bf16x8 aK1 = *(const bf16x8*)&Ks[(32 + col) * LDK + ks * 16 + hl * 8];
      sT0 = __builtin_amdgcn_mfma_f32_32x32x16_bf16(aK0, bQ[ks], sT0, 0, 0, 0);
      sT1 = __builtin_amdgcn_mfma_f32_32x32x16_bf16(aK1, bQ[ks], sT1, 0, 0, 0);
    }
    unsigned pw[2][8];
#pragma unroll
    for (int kb = 0; kb < 2; ++kb) {
      const f32x16 sT = kb ? sT1 : sT0;
      float e[16];
#pragma unroll
      for (int g = 0; g < 4; ++g) {
        const int4 mv = mq[kb][g];
        const int* mvp = &mv.x;
#pragma unroll
        for (int r3 = 0; r3 < 4; ++r3) {
          const int reg = g * 4 + r3;
          const float bias = mvp[r3] ? CM : 0.0f;
          const float ev = __builtin_amdgcn_exp2f(fmaf(sT[reg], C1, bias));
          e[reg] = ev;
          lacc += ev;
        }
        pw[kb][g * 2 + 0] = packbf(e[g * 4 + 0], e[g * 4 + 1]);
        pw[kb][g * 2 + 1] = packbf(e[g * 4 + 2], e[g * 4 + 3]);
      }
    }
#pragma unroll
    for (int ks = 0; ks < 4; ++ks) {
      const int kb = ks >> 1, h = ks & 1;
      const unsigned d0 = pw[kb][4 * h + 0], d1 = pw[kb][4 * h + 1];
      const unsigned d2 = pw[kb][4 * h + 2], d3 = pw[kb][4 * h + 3];
      const unsigned s0 = hl ? d0 : d2;
      const unsigned s1 = hl ? d1 : d3;
      const unsigned r0 = (unsigned)__shfl_xor((int)s0, 32);
      const unsigned r1 = (unsigned)__shfl_xor((int)s1, 32);
      union { bf16x8 v; unsigned d[4]; } pf;
      pf.d[0] = hl ? r0 : d0;
      pf.d[1] = hl ? r1 : d1;
      pf.d[2] = hl ? d2 : r0;
      pf.d[3] = hl ? d3 : r1;
      const int cpr = 8 * (((2 * ks + hl) + sw) & 7);
      const bf16x8 aV0 = *(const bf16x8*)&Vt[col * LDV + cpr];
      const bf16x8 aV1 = *(const bf16x8*)&Vt[(32 + col) * LDV + cpr];
      oT0 = __builtin_amdgcn_mfma_f32_32x32x16_bf16(aV0, pf.v, oT0, 0, 0, 0);
      oT1 = __builtin_amdgcn_mfma_f32_32x32x16_bf16(aV1, pf.v, oT1, 0, 0, 0);
    }
  }
  const float ltot = lacc + __shfl_xor(lacc, 32);
  const float inv = 1.0f / ltot;
  float* orow = out + hoff + (size_t)qg * D_DIM;
#pragma unroll
  for (int rg = 0; rg < 4; ++rg) {
    float4 w0, w1;
    w0.x = oT0[rg * 4 + 0] * inv; w0.y = oT0[rg * 4 + 1] * inv;
    w0.z = oT0[rg * 4 + 2] * inv; w0.w = oT0[rg * 4 + 3] * inv;
    w1.x = oT1[rg * 4 + 0] * inv; w1.y = oT1[rg * 4 + 1] * inv;
    w1.z = oT1[rg * 4 + 2] * inv; w1.w = oT1[rg * 4 + 3] * inv;
    *(float4*)(orow + 8 * rg + 4 * hl) = w0;
    *(float4*)(orow + 32 + 8 * rg + 4 * hl) = w1;
  }
}

extern "C" void kernel_launch(void* const* d_in, const int* in_sizes, int n_in,
                              void* d_out, int out_size, void* d_ws, size_t ws_size,
                              hipStream_t stream) {
  const float* q = (const float*)d_in[0];
  const float* k = (const float*)d_in[1];
  const float* v = (const float*)d_in[2];
  const int* mask = (const int*)d_in[3];
  float* out = (float*)d_out;

  const size_t img_elems = (size_t)NBH * N_KT * TILE_FR;  // shorts (per image)
  const size_t mw_words = (size_t)N_KT * S_LEN * 2 * 16;  // u32 count
  const size_t need = img_elems * 2 * sizeof(unsigned short) + mw_words * 4;

  if (ws_size >= need) {
    unsigned short* kfw = (unsigned short*)d_ws;
    unsigned short* vfw = kfw + img_elems;
    u32* mwp = (u32*)(vfw + img_elems);
    prep_kvf<<<dim3(N_KT, NBH), dim3(256), 0, stream>>>(k, v, kfw, vfw);
    prep_mask<<<dim3((S_LEN * N_KT) / 4), dim3(256), 0, stream>>>(mask, mwp);
    attn_fwd<<<dim3(S_LEN / 64, NBH), dim3(128), 0, stream>>>(q, kfw, vfw, mwp, out);
  } else {
    attn_fwd_self<<<dim3(S_LEN / 128, NBH), dim3(256), 0, stream>>>(q, k, v, mask, out);
  }
}